// Round 4
// baseline (218.226 us; speedup 1.0000x reference)
//
#include <hip/hip_runtime.h>

#define CIN    128
#define COUT   256
#define Hh     112
#define Ww     112
#define HW     12544          // 112*112
#define NBATCH 8
#define NPIX   (NBATCH*HW)    // 100352
#define KD     (CIN*9)        // 1152
#define PH     114            // padded H/W
#define PPIX   (NBATCH*PH*PH) // padded pixel count

// fused prep grid sections
#define G_SQ   784            // NPIX/128 transpose blocks
#define G_BORD 226            // 8*452*16 / 256 border-zero blocks
#define G_PACK 288            // 294912/4/256 weight-pack blocks

typedef __bf16         v8bf __attribute__((ext_vector_type(8)));
typedef float          v4f  __attribute__((ext_vector_type(4)));

__device__ __forceinline__ unsigned short f2bf(float f) {
  unsigned int u = __float_as_uint(f);
  u += 0x7FFFu + ((u >> 16) & 1u);   // round-to-nearest-even
  return (unsigned short)(u >> 16);
}

__device__ __forceinline__ void gl_lds16(const void* g, void* l) {
  __builtin_amdgcn_global_load_lds(
      (const __attribute__((address_space(1))) void*)g,
      (__attribute__((address_space(3))) void*)l, 16, 0, 0);
}

// ---------------------------------------------------------------------------
// Fused prep kernel, grid-sectioned:
//  [0, G_SQ):               transpose 128 px x 128 ch -> padded channels-last
//                           bf16 + per-pixel sum(x^2)
//  [G_SQ, G_SQ+G_BORD):     zero 1-px border of xbp
//  [.., +G_PACK):           pack weights wp[o][(kh*3+kw)*128+c]
// ---------------------------------------------------------------------------
#define USS 65   // uint-stride of LDS pixel row (64 + 1 pad)
__global__ __launch_bounds__(256) void k_prep(
    const float* __restrict__ x, const float* __restrict__ w,
    unsigned short* __restrict__ xbp, float* __restrict__ sq,
    unsigned short* __restrict__ wp)
{
  int bid = blockIdx.x;
  int tid = threadIdx.x;

  if (bid < G_SQ) {
    // ---- transpose + sum(x^2): 128 contiguous pixels, all 128 channels ----
    __shared__ unsigned int US[128 * USS];   // 33,280 B
    __shared__ float sqp[4 * 128];

    int l   = tid & 63;
    int wid = tid >> 6;
    int P0  = bid * 128;            // 128 | HW -> never crosses batch
    int b   = P0 / HW;
    int r0  = P0 - b * HW;

    const float* xb0 = x + (size_t)b * CIN * HW + r0;
    float ax = 0.0f, ay = 0.0f;
#pragma unroll
    for (int i = 0; i < 16; ++i) {
      int c = wid * 32 + i * 2;     // channel pair (c, c+1)
      float2 v0 = ((const float2*)(xb0 + (size_t)c * HW))[l];       // 512B/instr
      float2 v1 = ((const float2*)(xb0 + (size_t)(c + 1) * HW))[l];
      ax += v0.x * v0.x + v1.x * v1.x;
      ay += v0.y * v0.y + v1.y * v1.y;
      int c2 = wid * 16 + i;
      US[(2 * l) * USS + c2]     = (unsigned int)f2bf(v0.x) | ((unsigned int)f2bf(v1.x) << 16);
      US[(2 * l + 1) * USS + c2] = (unsigned int)f2bf(v0.y) | ((unsigned int)f2bf(v1.y) << 16);
    }
    sqp[wid * 128 + 2 * l]     = ax;
    sqp[wid * 128 + 2 * l + 1] = ay;
    __syncthreads();

    if (tid < 128)
      sq[P0 + tid] = sqp[tid] + sqp[128 + tid] + sqp[256 + tid] + sqp[384 + tid];

    // coalesced channels-last store: 128 px x 16 chunks of 16B
    unsigned int* xout = (unsigned int*)xbp;
#pragma unroll
    for (int it = 0; it < 8; ++it) {
      int h  = it * 256 + tid;
      int px = h >> 4, cu = (h & 15) * 4;
      const unsigned int* s = &US[px * USS + cu];
      uint4 v; v.x = s[0]; v.y = s[1]; v.z = s[2]; v.w = s[3];
      int p  = P0 + px;
      int rr = p - b * HW;
      int oy = rr / Ww, ox = rr - oy * Ww;
      *(uint4*)(xout + ((size_t)(b * PH + oy + 1) * PH + (ox + 1)) * 64 + cu) = v;
    }
    return;
  }

  if (bid < G_SQ + G_BORD) {
    // ---- zero border: 8 images x 452 border px x 16 chunks ----
    int h   = (bid - G_SQ) * 256 + tid;     // < 57,856
    int img = h / (452 * 16);
    int rem = h - img * (452 * 16);
    int bp  = rem >> 4;
    int cu  = (rem & 15) * 4;
    int y, xq;
    if      (bp < 114) { y = 0;        xq = bp; }
    else if (bp < 228) { y = PH - 1;   xq = bp - 114; }
    else if (bp < 340) { y = bp - 227; xq = 0; }
    else               { y = bp - 339; xq = PH - 1; }
    uint4 z = {0, 0, 0, 0};
    *(uint4*)((unsigned int*)xbp + ((size_t)(img * PH + y) * PH + xq) * 64 + cu) = z;
    return;
  }

  // ---- pack weights: uint2 = 4 channels of wp[o][kk*128 + c] ----
  int idx = (bid - G_SQ - G_BORD) * 256 + tid;   // < 73,728
  int o   = idx / 288;
  int rem = idx - o * 288;
  int kk  = rem >> 5;
  int c0  = (rem & 31) * 4;
  const float* ws = w + (size_t)o * KD + kk;
  unsigned int p0 = (unsigned int)f2bf(ws[(c0 + 0) * 9]) | ((unsigned int)f2bf(ws[(c0 + 1) * 9]) << 16);
  unsigned int p1 = (unsigned int)f2bf(ws[(c0 + 2) * 9]) | ((unsigned int)f2bf(ws[(c0 + 3) * 9]) << 16);
  uint2 pk; pk.x = p0; pk.y = p1;
  *(uint2*)((unsigned int*)wp + ((size_t)o * KD + kk * 128 + c0) / 2) = pk;
}

// ---------------------------------------------------------------------------
// Kernel C: implicit GEMM, LDS staging via global_load_lds(16B), BK=64,
// 128x128 tile, 18 K-steps. Inline 3x3 invnorm from sq in the epilogue;
// output through padded LDS slab for fully coalesced stores.
// ---------------------------------------------------------------------------
#define SLAB_S 132   // fp32 slab stride
__global__ __launch_bounds__(256, 3) void k_conv(
    const unsigned short* __restrict__ wp,
    const unsigned short* __restrict__ xbp,
    const float* __restrict__ sq,
    const float* __restrict__ bias,
    float* __restrict__ out)
{
  __shared__ __align__(16) char smem[64 * SLAB_S * 4];   // 33,792 B
  unsigned short* As = (unsigned short*)smem;            // [128][64]
  unsigned short* Bs = As + 128 * 64;                    // [128][64]
  float* slab = (float*)smem;                            // [64][SLAB_S]

  int tid  = threadIdx.x;
  int lane = tid & 63;
  int wid  = tid >> 6;
  int wm   = wid >> 1, wn = wid & 1;
  int quad = lane >> 4;
  int l16  = lane & 15;

  // XCD-paired swizzle: both bm of one bn land on the same XCD (adjacent %8)
  int L  = blockIdx.x;           // 0..1567
  int g  = L >> 4;
  int j  = L & 15;
  int bn = g * 8 + (j & 7);      // 0..783
  int bm = j >> 3;               // 0..1

  int srow = tid >> 3;
  int g16  = (tid & 7) ^ (srow & 7);

  const unsigned short* asrc = wp + (size_t)(bm * 128 + srow) * KD + g16 * 8;

  int pb[4];
#pragma unroll
  for (int jj = 0; jj < 4; ++jj) {
    int n  = bn * 128 + jj * 32 + srow;
    int b  = n / HW;  int r  = n - b * HW;
    int oy = r / Ww;  int ox = r - oy * Ww;
    pb[jj] = ((b * PH + oy) * PH + ox) * CIN + g16 * 8;
  }

  v4f acc[4][4];
#pragma unroll
  for (int mt = 0; mt < 4; ++mt)
#pragma unroll
    for (int nt = 0; nt < 4; ++nt)
#pragma unroll
      for (int q = 0; q < 4; ++q) acc[mt][nt][q] = 0.0f;

  const int khs[9] = {0,0,0,1,1,1,2,2,2};
  const int kws[9] = {0,1,2,0,1,2,0,1,2};

  for (int s = 0; s < 18; ++s) {
    int kk   = s >> 1;
    int c0   = (s & 1) * 64;
    int soff = (khs[kk] * PH + kws[kk]) * CIN + c0;

#pragma unroll
    for (int jj = 0; jj < 4; ++jj)
      gl_lds16(asrc + (size_t)jj * 32 * KD + s * 64,
               &As[(wid * 8 + jj * 32) * 64]);
#pragma unroll
    for (int jj = 0; jj < 4; ++jj)
      gl_lds16(xbp + pb[jj] + soff,
               &Bs[(wid * 8 + jj * 32) * 64]);

    __syncthreads();

#pragma unroll
    for (int h = 0; h < 2; ++h) {
      v8bf af[4], bf[4];
      int cch = (h * 4 + quad) ^ (l16 & 7);
#pragma unroll
      for (int mt = 0; mt < 4; ++mt)
        af[mt] = *(const v8bf*)&As[(wm * 64 + mt * 16 + l16) * 64 + cch * 8];
#pragma unroll
      for (int nt = 0; nt < 4; ++nt)
        bf[nt] = *(const v8bf*)&Bs[(wn * 64 + nt * 16 + l16) * 64 + cch * 8];
#pragma unroll
      for (int mt = 0; mt < 4; ++mt)
#pragma unroll
        for (int nt = 0; nt < 4; ++nt)
          acc[mt][nt] = __builtin_amdgcn_mfma_f32_16x16x32_bf16(
              af[mt], bf[nt], acc[mt][nt], 0, 0, 0);
    }

    __syncthreads();
  }

  // ------------- epilogue -----------------------------------------------
  int nbase = bn * 128;
  int bb = nbase / HW;           // 128 | HW: tile within one batch image
  int rr = nbase - bb * HW;
  float* obase = out + (size_t)bb * COUT * HW + rr;
  const float* sqb = sq + (size_t)bb * HW;

  // inline 3x3 box-sum invnorm (sq is L2/L3-resident, 0.4 MB)
  float invv[4];
#pragma unroll
  for (int nt = 0; nt < 4; ++nt) {
    int off = wn * 64 + nt * 16 + l16;
    int rr2 = rr + off;
    int oy = rr2 / Ww, ox = rr2 - oy * Ww;
    float ssum = 0.0f;
#pragma unroll
    for (int dy = -1; dy <= 1; ++dy) {
      int iy = oy + dy;
      if ((unsigned)iy >= (unsigned)Hh) continue;
#pragma unroll
      for (int dx = -1; dx <= 1; ++dx) {
        int ix = ox + dx;
        if ((unsigned)ix >= (unsigned)Ww) continue;
        ssum += sqb[iy * Ww + ix];
      }
    }
    invv[nt] = 1.0f / fmaxf(sqrtf(ssum), 1e-12f);
  }

  for (int pass = 0; pass < 2; ++pass) {
    if (pass) __syncthreads();
    if (wm == pass) {
#pragma unroll
      for (int mt = 0; mt < 4; ++mt)
#pragma unroll
        for (int nt = 0; nt < 4; ++nt) {
          int col = wn * 64 + nt * 16 + l16;
#pragma unroll
          for (int reg = 0; reg < 4; ++reg)
            slab[(mt * 16 + quad * 4 + reg) * SLAB_S + col] =
                acc[mt][nt][reg] * invv[nt];
        }
    }
    __syncthreads();
#pragma unroll
    for (int it = 0; it < 2; ++it) {
      int row = it * 32 + (tid >> 3);
      int o   = bm * 128 + pass * 64 + row;
      float bv = bias[o];
      float* orow = obase + (size_t)o * HW;
#pragma unroll
      for (int k = 0; k < 4; ++k) {
        int c4 = ((tid & 7) + k * 8) * 4;
        v4f v = *(const v4f*)&slab[row * SLAB_S + c4];
        v4f r2;
#pragma unroll
        for (int q = 0; q < 4; ++q) r2[q] = v[q] + bv;
        *(v4f*)(orow + c4) = r2;           // 8 lanes -> 128B contiguous
      }
    }
  }
}

// ---------------------------------------------------------------------------
extern "C" void kernel_launch(void* const* d_in, const int* in_sizes, int n_in,
                              void* d_out, int out_size, void* d_ws, size_t ws_size,
                              hipStream_t stream) {
  const float* x    = (const float*)d_in[0];  // [8,128,112,112]
  const float* w    = (const float*)d_in[1];  // [256,128,3,3]
  const float* bias = (const float*)d_in[2];  // [256]
  float* out        = (float*)d_out;          // [8,256,112,112]

  char* ws = (char*)d_ws;
  unsigned short* xbp = (unsigned short*)ws;                   // 26,615,808 B
  size_t off = (size_t)PPIX * CIN * 2;
  unsigned short* wpk = (unsigned short*)(ws + off);           // 589,824 B
  off += (size_t)COUT * KD * 2;
  float* sq = (float*)(ws + off);                              // 401,408 B

  k_prep<<<G_SQ + G_BORD + G_PACK, 256, 0, stream>>>(x, w, xbp, sq, wpk);
  k_conv<<<1568, 256, 0, stream>>>(wpk, xbp, sq, bias, out);
}